// Round 10
// baseline (224.166 us; speedup 1.0000x reference)
//
#include <hip/hip_runtime.h>
#include <hip/hip_bf16.h>

using f32x4   = __attribute__((ext_vector_type(4))) float;
using short8  = __attribute__((ext_vector_type(8))) short;
using short4v = __attribute__((ext_vector_type(4))) short;

#define LOG2_2PI 2.6514961294723187f   // log2(2*pi)
#define L2E_HALF 0.7213475204444817f   // 0.5*log2(e)
#define HP2 640   // padded phoneme axis (10 x 64-chunks; 1280B encT rows)

__device__ __forceinline__ short bf16bits(float x) {
  unsigned u = __builtin_bit_cast(unsigned, x);
  u = (u + 0x7FFFu + ((u >> 16) & 1u)) >> 16;   // RNE; inputs are finite
  return (short)u;
}
__device__ __forceinline__ float bf16round(float x) {
  unsigned u = __builtin_bit_cast(unsigned, x);
  u = ((u + 0x7FFFu + ((u >> 16) & 1u)) >> 16) << 16;
  return __builtin_bit_cast(float, u);
}

// Kernel 0: packed params pk[b][h] = {c, q2, b2, 0}; b2 = -1e30 for h >= L
// (masking baked in; h in [L, HP2) gives exp2(-inf) = 0 downstream).
__global__ void prep_kernel(const float* __restrict__ dur,
                            const float* __restrict__ vars,
                            const int* __restrict__ lens,
                            f32x4* __restrict__ pk, int H) {
  const int b = blockIdx.x;
  const int l = threadIdx.x;
  const int L = lens[b];
  float run = 0.f;
  for (int h0 = 0; h0 < HP2; h0 += 64) {
    const int h = h0 + l;
    const float d = (h < H) ? dur[(size_t)b * H + h] : 0.f;
    float x = d;
#pragma unroll
    for (int off = 1; off < 64; off <<= 1) {
      float y = __shfl_up(x, off);
      if (l >= off) x += y;
    }
    f32x4 e = (f32x4){0.f, 0.f, -1e30f, 0.f};
    if (h < H) {
      const float v = vars[(size_t)b * H + h];
      e[0] = run + x - 0.5f * d;
      e[1] = L2E_HALF / v;
      e[2] = (h < L) ? -0.5f * (LOG2_2PI + __builtin_amdgcn_logf(v)) : -1e30f;
    }
    pk[(size_t)b * HP2 + h] = e;
    run += __shfl(x, 63);
  }
}

// Kernel 1 (win3): per (b, 32-frame tile) exact per-frame max + near-exact
// minimal window, computed from an LDS-staged copy of pk with broadcast
// reads. One thread per frame; single pass with running threshold (the
// accepted set is a superset of {h : s > final_max - 66} -> conservative).
__global__ void win3_kernel(const f32x4* __restrict__ pk,
                            const int* __restrict__ lens,
                            float* __restrict__ mArr, int* __restrict__ win,
                            int T, int TT, int TPB) {
  __shared__ __align__(16) f32x4 spk[HP2];
  __shared__ int sLo[32], sHi[32];

  const int b     = blockIdx.y;
  const int tile0 = blockIdx.x * TPB;
  const int nt    = min(TPB, TT - tile0);
  if (nt <= 0) return;
  const int L   = lens[b];
  const int tid = threadIdx.x;

  for (int i = tid; i < HP2; i += 256) spk[i] = pk[(size_t)b * HP2 + i];
  if (tid < 32) { sLo[tid] = 1 << 30; sHi[tid] = -1; }
  __syncthreads();

  for (int fl = tid; fl < nt * 32; fl += 256) {
    const int t = tile0 * 32 + fl;
    const float tA = (float)t;
    float m = -3.0e38f;
    int lo = 1 << 30, hi = -1;
    for (int h = 0; h < L; ++h) {
      const f32x4 v = spk[h];
      const float dd = tA - v[0];
      const float s = fmaf(-dd * dd, v[1], v[2]);
      m = fmaxf(m, s);
      if (s > m - 66.f) { lo = min(lo, h); hi = max(hi, h); }
    }
    if (t < T) {
      mArr[(size_t)b * TT * 32 + t] = m;
      atomicMin(&sLo[fl >> 5], lo);
      atomicMax(&sHi[fl >> 5], hi);
    }
  }
  __syncthreads();
  if (tid < nt && tile0 + tid < TT) {
    win[(b * TT + tile0 + tid) * 2 + 0] = sLo[tid] >> 6;
    win[(b * TT + tile0 + tid) * 2 + 1] = (sHi[tid] + 64) >> 6;
  }
}

// Kernel 2: enc [B][H][D] f32 -> encT [B][D][HP2] bf16. Chunks wholly beyond
// ceil(L/64)*64 are never read by gup (cHi <= ceil(L/64)) -> skip them.
__global__ void transpose_kernel(const float* __restrict__ enc,
                                 short* __restrict__ encT,
                                 const int* __restrict__ lens,
                                 int H, int D) {
  __shared__ short sT[64][66];
  const int b  = blockIdx.z;
  const int h0 = blockIdx.y * 64;
  const int d0 = blockIdx.x * 64;
  const int Lpad = (lens[b] + 63) & ~63;
  if (h0 >= Lpad) return;
  const int tid = threadIdx.x;

  const int dc = (tid & 15) * 4;
  const int hr = tid >> 4;
#pragma unroll
  for (int ps = 0; ps < 4; ++ps) {
    const int hh = hr + ps * 16;
    const int h  = h0 + hh;
    f32x4 v = (h < H) ? *(const f32x4*)&enc[((size_t)b * H + h) * D + d0 + dc]
                      : (f32x4){0.f, 0.f, 0.f, 0.f};
#pragma unroll
    for (int j = 0; j < 4; ++j) sT[dc + j][hh] = bf16bits(v[j]);
  }
  __syncthreads();

  const int tx4 = (tid & 15) * 4;
  const int ty2 = tid >> 4;
#pragma unroll
  for (int i = 0; i < 4; ++i) {
    const int d = d0 + ty2 + i * 16;
    short4v v;
#pragma unroll
    for (int j = 0; j < 4; ++j) v[j] = sT[ty2 + i * 16][tx4 + j];
    *(short4v*)&encT[((size_t)b * D + d) * HP2 + h0 + tx4] = v;
  }
}

// Main fused kernel: block = (32-frame tile, d-half, batch), 256 threads =
// 4 waves; wave w owns d in [dbase+64w, +64). Exact precomputed window
// (typically 1 chunk) + precomputed per-frame max; params read directly from
// global (L1-broadcast); LDS = weight tile only.
__launch_bounds__(256, 4)
__global__ void gup_kernel(const short* __restrict__ encT,
                           const f32x4* __restrict__ pk,
                           const int* __restrict__ win,
                           const float* __restrict__ mArr,
                           float* __restrict__ out,
                           int T, int TT) {
  constexpr int D  = 512;
  constexpr int AS = 72;           // sA row stride in halves (144B, 16B-aligned)

  __shared__ float sden[32];
  __shared__ short sA[2][32 * AS];

  const int tid   = threadIdx.x;
  const int b     = blockIdx.y;
  const int tIdx  = blockIdx.x >> 1;
  const int t0    = tIdx * 32;
  const int dbase = (blockIdx.x & 1) * 256;

  const int cLo  = win[(b * TT + tIdx) * 2 + 0];
  const int nC   = win[(b * TT + tIdx) * 2 + 1] - cLo;
  const int base = cLo * 64;

  const int tfA = tid >> 3;               // frame 0..31
  const int hs8 = tid & 7;
  const int k8  = hs8 * 8;                // this thread's 8 k-slots
  const float tA = (float)(t0 + tfA);
  const float mA = mArr[(size_t)b * TT * 32 + t0 + tfA];

  const int lane = tid & 63;
  const int wv   = tid >> 6;
  const int l15  = lane & 15;
  const int lq   = lane >> 4;

  f32x4 acc[2][4];
#pragma unroll
  for (int i = 0; i < 2; ++i)
#pragma unroll
    for (int j = 0; j < 4; ++j) acc[i][j] = (f32x4){0.f, 0.f, 0.f, 0.f};

  float denAcc = 0.f;
  const f32x4* pc = pk + (size_t)b * HP2 + base + k8;
  const short* bp = encT + ((size_t)b * D + dbase + wv * 64 + l15) * HP2 + base + lq * 8;

  int p = 0;
  for (int cc = 0; cc < nC; ++cc, p ^= 1) {
    // A tile: w = exp2(score - m), bf16 (RNE); params straight from global
    short8 w;
#pragma unroll
    for (int j = 0; j < 8; ++j) {
      const f32x4 v = pc[cc * 64 + j];
      const float dd = tA - v[0];
      const float pv = __builtin_amdgcn_exp2f(fmaf(-dd * dd, v[1], v[2]) - mA);
      w[j] = bf16bits(pv);
      denAcc += bf16round(pv);
    }
    *(short8*)&sA[p][tfA * AS + k8] = w;
    __syncthreads();

    // two 32-k sub-steps
#pragma unroll
    for (int kh = 0; kh < 2; ++kh) {
      short8 bfv[4];
#pragma unroll
      for (int nt = 0; nt < 4; ++nt)
        bfv[nt] = *(const short8*)(bp + (size_t)nt * 16 * HP2 + cc * 64 + kh * 32);
      short8 af[2];
#pragma unroll
      for (int mt = 0; mt < 2; ++mt)
        af[mt] = *(short8*)&sA[p][(mt * 16 + l15) * AS + kh * 32 + lq * 8];
      // swapped operands: acc holds C[d][t] -> lane gets 4 consecutive d
#pragma unroll
      for (int mt = 0; mt < 2; ++mt)
#pragma unroll
        for (int nt = 0; nt < 4; ++nt)
          acc[mt][nt] = __builtin_amdgcn_mfma_f32_16x16x32_bf16(bfv[nt], af[mt], acc[mt][nt], 0, 0, 0);
    }
    // single barrier per chunk: double-buffered sA handles WAR across iters.
  }

  // denominators: reduce the 8 threads sharing a frame
  {
    float dsum = denAcc;
    dsum += __shfl_xor(dsum, 1);
    dsum += __shfl_xor(dsum, 2);
    dsum += __shfl_xor(dsum, 4);
    if (hs8 == 0) sden[tfA] = dsum;
  }
  __syncthreads();

  // epilogue: normalize and store float4 (4 consecutive d per thread)
#pragma unroll
  for (int mt = 0; mt < 2; ++mt) {
    const int tg = t0 + mt * 16 + l15;
    const float inv = 1.0f / sden[mt * 16 + l15];
    if (tg < T) {
#pragma unroll
      for (int nt = 0; nt < 4; ++nt) {
        f32x4 o;
#pragma unroll
        for (int i = 0; i < 4; ++i) o[i] = acc[mt][nt][i] * inv;
        *(f32x4*)&out[((size_t)b * T + tg) * D + dbase + wv * 64 + nt * 16 + lq * 4] = o;
      }
    }
  }
}

extern "C" void kernel_launch(void* const* d_in, const int* in_sizes, int n_in,
                              void* d_out, int out_size, void* d_ws, size_t ws_size,
                              hipStream_t stream) {
  const float* enc  = (const float*)d_in[0];
  const float* dur  = (const float*)d_in[1];
  const float* vars = (const float*)d_in[2];
  const int*   lens = (const int*)d_in[3];

  const int B = in_sizes[3];
  const int H = in_sizes[1] / B;
  const int D = in_sizes[0] / in_sizes[1];
  const int T = out_size / (B * D);
  const int TT = (T + 31) / 32;
  (void)n_in; (void)ws_size;

  f32x4* pk   = (f32x4*)d_ws;                         // B*HP2 float4
  int*   wn   = (int*)(pk + (size_t)B * HP2);         // B*TT*2
  float* mArr = (float*)(wn + (size_t)B * TT * 2);    // B*TT*32
  short* encT = (short*)(mArr + (size_t)B * TT * 32); // B*D*HP2 bf16 ~= 21 MB

  prep_kernel<<<B, 64, 0, stream>>>(dur, vars, lens, pk, H);

  const int NBW = 16;
  const int TPB = (TT + NBW - 1) / NBW;
  dim3 wgrid(NBW, B);
  win3_kernel<<<wgrid, 256, 0, stream>>>(pk, lens, mArr, wn, T, TT, TPB);

  dim3 tgrid(D / 64, HP2 / 64, B);
  transpose_kernel<<<tgrid, 256, 0, stream>>>(enc, encT, lens, H, D);

  dim3 grid(TT * 2, B);
  gup_kernel<<<grid, 256, 0, stream>>>(encT, pk, wn, mArr, (float*)d_out, T, TT);
}

// Round 11
// 110.734 us; speedup vs baseline: 2.0244x; 2.0244x over previous
//
#include <hip/hip_runtime.h>
#include <hip/hip_bf16.h>

using f32x4   = __attribute__((ext_vector_type(4))) float;
using short8  = __attribute__((ext_vector_type(8))) short;
using short4v = __attribute__((ext_vector_type(4))) short;

#define LOG2_2PI 2.6514961294723187f   // log2(2*pi)
#define L2E_HALF 0.7213475204444817f   // 0.5*log2(e)
#define HP2 640   // padded phoneme axis (10 x 64-chunks; 1280B encT rows)

__device__ __forceinline__ short bf16bits(float x) {
  unsigned u = __builtin_bit_cast(unsigned, x);
  u = (u + 0x7FFFu + ((u >> 16) & 1u)) >> 16;   // RNE; inputs are finite
  return (short)u;
}
__device__ __forceinline__ float bf16round(float x) {
  unsigned u = __builtin_bit_cast(unsigned, x);
  u = ((u + 0x7FFFu + ((u >> 16) & 1u)) >> 16) << 16;
  return __builtin_bit_cast(float, u);
}

// Kernel 0: packed params pk[b][h] = {c, q2, b2, 0}; b2 = -1e30 for h >= L
// (masking baked in; h in [L, HP2) gives exp2(-inf) = 0 downstream).
__global__ void prep_kernel(const float* __restrict__ dur,
                            const float* __restrict__ vars,
                            const int* __restrict__ lens,
                            f32x4* __restrict__ pk, int H) {
  const int b = blockIdx.x;
  const int l = threadIdx.x;
  const int L = lens[b];
  float run = 0.f;
  for (int h0 = 0; h0 < HP2; h0 += 64) {
    const int h = h0 + l;
    const float d = (h < H) ? dur[(size_t)b * H + h] : 0.f;
    float x = d;
#pragma unroll
    for (int off = 1; off < 64; off <<= 1) {
      float y = __shfl_up(x, off);
      if (l >= off) x += y;
    }
    f32x4 e = (f32x4){0.f, 0.f, -1e30f, 0.f};
    if (h < H) {
      const float v = vars[(size_t)b * H + h];
      e[0] = run + x - 0.5f * d;
      e[1] = L2E_HALF / v;
      e[2] = (h < L) ? -0.5f * (LOG2_2PI + __builtin_amdgcn_logf(v)) : -1e30f;
    }
    pk[(size_t)b * HP2 + h] = e;
    run += __shfl(x, 63);
  }
}

// Kernel 1 (win3, two-pass exact): per (b, 32-frame tile) exact per-frame
// max + exact minimal window {h : s > m - 66}, from an LDS-staged copy of pk
// with broadcast reads. One thread per frame.
__global__ void win3_kernel(const f32x4* __restrict__ pk,
                            const int* __restrict__ lens,
                            float* __restrict__ mArr, int* __restrict__ win,
                            int T, int TT, int TPB) {
  __shared__ __align__(16) f32x4 spk[HP2];
  __shared__ int sLo[32], sHi[32];

  const int b     = blockIdx.y;
  const int tile0 = blockIdx.x * TPB;
  const int nt    = min(TPB, TT - tile0);
  if (nt <= 0) return;
  const int L   = lens[b];
  const int tid = threadIdx.x;

  for (int i = tid; i < HP2; i += 256) spk[i] = pk[(size_t)b * HP2 + i];
  if (tid < 32) { sLo[tid] = 1 << 30; sHi[tid] = -1; }
  __syncthreads();

  for (int fl = tid; fl < nt * 32; fl += 256) {
    const int t = tile0 * 32 + fl;
    const float tA = (float)t;

    // pass 1: exact final max
    float m = -3.0e38f;
    for (int h = 0; h < L; ++h) {
      const f32x4 v = spk[h];
      const float dd = tA - v[0];
      m = fmaxf(m, fmaf(-dd * dd, v[1], v[2]));
    }
    // pass 2: exact window vs final threshold
    const float thr = m - 66.f;
    int lo = 1 << 30, hi = -1;
    for (int h = 0; h < L; ++h) {
      const f32x4 v = spk[h];
      const float dd = tA - v[0];
      const float s = fmaf(-dd * dd, v[1], v[2]);
      if (s > thr) { lo = min(lo, h); hi = max(hi, h); }
    }
    if (t < T) {
      mArr[(size_t)b * TT * 32 + t] = m;
      atomicMin(&sLo[fl >> 5], lo);
      atomicMax(&sHi[fl >> 5], hi);
    }
  }
  __syncthreads();
  if (tid < nt && tile0 + tid < TT) {
    int lo = sLo[tid], hi = sHi[tid];
    if (hi < lo) { lo = 0; hi = 0; }
    win[(b * TT + tile0 + tid) * 2 + 0] = lo >> 6;
    win[(b * TT + tile0 + tid) * 2 + 1] = (hi + 64) >> 6;
  }
}

// Kernel 2: enc [B][H][D] f32 -> encT [B][D][HP2] bf16. Chunks wholly beyond
// ceil(L/64)*64 are never read by gup (cHi <= ceil(L/64)) -> skip them.
__global__ void transpose_kernel(const float* __restrict__ enc,
                                 short* __restrict__ encT,
                                 const int* __restrict__ lens,
                                 int H, int D) {
  __shared__ short sT[64][66];
  const int b  = blockIdx.z;
  const int h0 = blockIdx.y * 64;
  const int d0 = blockIdx.x * 64;
  const int Lpad = (lens[b] + 63) & ~63;
  if (h0 >= Lpad) return;
  const int tid = threadIdx.x;

  const int dc = (tid & 15) * 4;
  const int hr = tid >> 4;
#pragma unroll
  for (int ps = 0; ps < 4; ++ps) {
    const int hh = hr + ps * 16;
    const int h  = h0 + hh;
    f32x4 v = (h < H) ? *(const f32x4*)&enc[((size_t)b * H + h) * D + d0 + dc]
                      : (f32x4){0.f, 0.f, 0.f, 0.f};
#pragma unroll
    for (int j = 0; j < 4; ++j) sT[dc + j][hh] = bf16bits(v[j]);
  }
  __syncthreads();

  const int tx4 = (tid & 15) * 4;
  const int ty2 = tid >> 4;
#pragma unroll
  for (int i = 0; i < 4; ++i) {
    const int d = d0 + ty2 + i * 16;
    short4v v;
#pragma unroll
    for (int j = 0; j < 4; ++j) v[j] = sT[ty2 + i * 16][tx4 + j];
    *(short4v*)&encT[((size_t)b * D + d) * HP2 + h0 + tx4] = v;
  }
}

// Main fused kernel: block = (32-frame tile, d-half, batch), 256 threads =
// 4 waves; wave w owns d in [dbase+64w, +64). Exact precomputed window
// (typically 1 chunk) + precomputed per-frame max; params read directly from
// global (L1-broadcast); LDS = weight tile only.
__launch_bounds__(256, 4)
__global__ void gup_kernel(const short* __restrict__ encT,
                           const f32x4* __restrict__ pk,
                           const int* __restrict__ win,
                           const float* __restrict__ mArr,
                           float* __restrict__ out,
                           int T, int TT) {
  constexpr int D  = 512;
  constexpr int AS = 72;           // sA row stride in halves (144B, 16B-aligned)

  __shared__ float sden[32];
  __shared__ short sA[2][32 * AS];

  const int tid   = threadIdx.x;
  const int b     = blockIdx.y;
  const int tIdx  = blockIdx.x >> 1;
  const int t0    = tIdx * 32;
  const int dbase = (blockIdx.x & 1) * 256;

  const int cLo  = win[(b * TT + tIdx) * 2 + 0];
  const int nC   = win[(b * TT + tIdx) * 2 + 1] - cLo;
  const int base = cLo * 64;

  const int tfA = tid >> 3;               // frame 0..31
  const int hs8 = tid & 7;
  const int k8  = hs8 * 8;                // this thread's 8 k-slots
  const float tA = (float)(t0 + tfA);
  const float mA = mArr[(size_t)b * TT * 32 + t0 + tfA];

  const int lane = tid & 63;
  const int wv   = tid >> 6;
  const int l15  = lane & 15;
  const int lq   = lane >> 4;

  f32x4 acc[2][4];
#pragma unroll
  for (int i = 0; i < 2; ++i)
#pragma unroll
    for (int j = 0; j < 4; ++j) acc[i][j] = (f32x4){0.f, 0.f, 0.f, 0.f};

  float denAcc = 0.f;
  const f32x4* pc = pk + (size_t)b * HP2 + base + k8;
  const short* bp = encT + ((size_t)b * D + dbase + wv * 64 + l15) * HP2 + base + lq * 8;

  int p = 0;
  for (int cc = 0; cc < nC; ++cc, p ^= 1) {
    // A tile: w = exp2(score - m), bf16 (RNE); params straight from global
    short8 w;
#pragma unroll
    for (int j = 0; j < 8; ++j) {
      const f32x4 v = pc[cc * 64 + j];
      const float dd = tA - v[0];
      const float pv = __builtin_amdgcn_exp2f(fmaf(-dd * dd, v[1], v[2]) - mA);
      w[j] = bf16bits(pv);
      denAcc += bf16round(pv);
    }
    *(short8*)&sA[p][tfA * AS + k8] = w;
    __syncthreads();

    // two 32-k sub-steps
#pragma unroll
    for (int kh = 0; kh < 2; ++kh) {
      short8 bfv[4];
#pragma unroll
      for (int nt = 0; nt < 4; ++nt)
        bfv[nt] = *(const short8*)(bp + (size_t)nt * 16 * HP2 + cc * 64 + kh * 32);
      short8 af[2];
#pragma unroll
      for (int mt = 0; mt < 2; ++mt)
        af[mt] = *(short8*)&sA[p][(mt * 16 + l15) * AS + kh * 32 + lq * 8];
      // swapped operands: acc holds C[d][t] -> lane gets 4 consecutive d
#pragma unroll
      for (int mt = 0; mt < 2; ++mt)
#pragma unroll
        for (int nt = 0; nt < 4; ++nt)
          acc[mt][nt] = __builtin_amdgcn_mfma_f32_16x16x32_bf16(bfv[nt], af[mt], acc[mt][nt], 0, 0, 0);
    }
    // single barrier per chunk: double-buffered sA handles WAR across iters.
  }

  // denominators: reduce the 8 threads sharing a frame
  {
    float dsum = denAcc;
    dsum += __shfl_xor(dsum, 1);
    dsum += __shfl_xor(dsum, 2);
    dsum += __shfl_xor(dsum, 4);
    if (hs8 == 0) sden[tfA] = dsum;
  }
  __syncthreads();

  // epilogue: normalize and store float4 (4 consecutive d per thread)
#pragma unroll
  for (int mt = 0; mt < 2; ++mt) {
    const int tg = t0 + mt * 16 + l15;
    const float inv = 1.0f / sden[mt * 16 + l15];
    if (tg < T) {
#pragma unroll
      for (int nt = 0; nt < 4; ++nt) {
        f32x4 o;
#pragma unroll
        for (int i = 0; i < 4; ++i) o[i] = acc[mt][nt][i] * inv;
        *(f32x4*)&out[((size_t)b * T + tg) * D + dbase + wv * 64 + nt * 16 + lq * 4] = o;
      }
    }
  }
}

extern "C" void kernel_launch(void* const* d_in, const int* in_sizes, int n_in,
                              void* d_out, int out_size, void* d_ws, size_t ws_size,
                              hipStream_t stream) {
  const float* enc  = (const float*)d_in[0];
  const float* dur  = (const float*)d_in[1];
  const float* vars = (const float*)d_in[2];
  const int*   lens = (const int*)d_in[3];

  const int B = in_sizes[3];
  const int H = in_sizes[1] / B;
  const int D = in_sizes[0] / in_sizes[1];
  const int T = out_size / (B * D);
  const int TT = (T + 31) / 32;
  (void)n_in; (void)ws_size;

  f32x4* pk   = (f32x4*)d_ws;                         // B*HP2 float4
  int*   wn   = (int*)(pk + (size_t)B * HP2);         // B*TT*2
  float* mArr = (float*)(wn + (size_t)B * TT * 2);    // B*TT*32
  short* encT = (short*)(mArr + (size_t)B * TT * 32); // B*D*HP2 bf16 ~= 21 MB

  prep_kernel<<<B, 64, 0, stream>>>(dur, vars, lens, pk, H);

  const int NBW = 16;
  const int TPB = (TT + NBW - 1) / NBW;
  dim3 wgrid(NBW, B);
  win3_kernel<<<wgrid, 256, 0, stream>>>(pk, lens, mArr, wn, T, TT, TPB);

  dim3 tgrid(D / 64, HP2 / 64, B);
  transpose_kernel<<<tgrid, 256, 0, stream>>>(enc, encT, lens, H, D);

  dim3 grid(TT * 2, B);
  gup_kernel<<<grid, 256, 0, stream>>>(encT, pk, wn, mArr, (float*)d_out, T, TT);
}